// Round 16
// baseline (500.313 us; speedup 1.0000x reference)
//
#include <hip/hip_runtime.h>
#include <hip/hip_bf16.h>
#include <cstdint>
#include <cstddef>

#define T_TOK 8192
#define MDIM  4096
#define NEXP  64
#define CAP   128
#define TEC   ((size_t)T_TOK * NEXP * CAP)        // 67,108,864
#define OUTN  ((size_t)(1 + 2 * TEC))             // 134,217,729 floats

typedef __attribute__((ext_vector_type(8))) short bf16x8;   // 8 bf16 = 4 VGPR
typedef __attribute__((ext_vector_type(4))) float f32x4;    // MFMA acc

// split f32 -> hi bf16 + lo bf16 (residual), |err| ~ 2^-18 relative
__device__ __forceinline__ void split8(const float* f, bf16x8& h, bf16x8& l) {
#pragma unroll
  for (int j = 0; j < 8; ++j) {
    const __hip_bfloat16 hb = __float2bfloat16(f[j]);
    const float r = f[j] - __bfloat162float(hb);
    h[j] = __builtin_bit_cast(short, hb);
    l[j] = __builtin_bit_cast(short, __float2bfloat16(r));
  }
}

// async global->LDS, 16 bytes per lane (linear LDS dest: wavebase + lane*16)
__device__ __forceinline__ void gll16(const void* g, void* l) {
  __builtin_amdgcn_global_load_lds(
      (const __attribute__((address_space(1))) void*)g,
      (__attribute__((address_space(3))) void*)l, 16, 0, 0);
}

template <int N>
__device__ __forceinline__ void vwait() {
  if constexpr (N == 0)      asm volatile("s_waitcnt vmcnt(0) lgkmcnt(0)" ::: "memory");
  else if constexpr (N == 1) asm volatile("s_waitcnt vmcnt(1) lgkmcnt(0)" ::: "memory");
  else                       asm volatile("s_waitcnt vmcnt(2) lgkmcnt(0)" ::: "memory");
}
__device__ __forceinline__ void barrier_now() {
  __builtin_amdgcn_s_barrier();
  asm volatile("" ::: "memory");
}

// ---------------------------------------------------------------------------
// One-time: wg (f32, [E][D]) -> wh/wl bf16 planes; zero esum + sync counters.
// ---------------------------------------------------------------------------
__global__ __launch_bounds__(256) void wsplit(
    const float* __restrict__ wg, short* __restrict__ wh,
    short* __restrict__ wl, float* __restrict__ esum, int* __restrict__ cnts) {
  const int i = blockIdx.x * 256 + threadIdx.x;       // float4 granule
  const float4 v = ((const float4*)wg)[i];
  const float a[4] = {v.x, v.y, v.z, v.w};
  short4 h, l;
  short* hp = &h.x; short* lp = &l.x;
#pragma unroll
  for (int j = 0; j < 4; ++j) {
    const __hip_bfloat16 hb = __float2bfloat16(a[j]);
    const float r = a[j] - __bfloat162float(hb);
    hp[j] = __builtin_bit_cast(short, hb);
    lp[j] = __builtin_bit_cast(short, __float2bfloat16(r));
  }
  ((short4*)wh)[i] = h;
  ((short4*)wl)[i] = l;
  if (blockIdx.x == 0 && threadIdx.x < NEXP) esum[threadIdx.x] = 0.f;
  if (blockIdx.x == 0 && threadIdx.x < 2)   cnts[threadIdx.x] = 0;
}

// ---------------------------------------------------------------------------
// SINGLE persistent fused kernel: GEMM + softmax + zero-fill + scan/scatter.
// Grid = 512 x 1024 thr, ALL co-resident (2 blk/CU: 144KB LDS, 32 waves,
// 416 VGPR/SIMD) -> device-scope spin-waits are deadlock-free regardless of
// dispatch order. Roles:
//   bid   0..255: GEMM (R15 structure verbatim) -> signal donecnt ->
//                 NT-fill tail (6 units) -> signal fillcnt
//   bid 256..495: NT-fill 27 units -> signal fillcnt
//   bid 496..511: NT-fill 11 units -> signal fillcnt -> spin donecnt==256 ->
//                 stage idx to LDS (overlaps fill tail) -> spin fillcnt==512
//                 -> per-expert ballot scan + scatter + l_aux
// Unit = 4096 float4 (64KB). 256*6 + 240*27 + 16*11 = 8192 units = exact
// cover of out[0 .. OUTN-2]; out[OUTN-1] by gemm block 0.
// ---------------------------------------------------------------------------
__global__ __launch_bounds__(1024, 8) void fused(
    const float* __restrict__ x, const short* __restrict__ wh,
    const short* __restrict__ wl, int* __restrict__ idx,
    float* __restrict__ gval, float* __restrict__ esum,
    int* __restrict__ cnts, float* __restrict__ out) {
  __shared__ __align__(16) char LDS[73728];           // 72 KB
  const int tid = threadIdx.x;
  const int bid = blockIdx.x;
  int* donecnt = cnts;
  int* fillcnt = cnts + 1;

  const f32x4 zv = {0.f, 0.f, 0.f, 0.f};
  f32x4* o4 = (f32x4*)out;

  auto ntfill = [&](long long startUnit, int iters) {
    size_t g = (size_t)startUnit * 4096 + tid;
#pragma unroll 4
    for (int i = 0; i < iters; ++i) {
      __builtin_nontemporal_store(zv, o4 + g);
      g += 1024;
    }
  };
  auto signal = [&](int* cnt) {
    asm volatile("s_waitcnt vmcnt(0) lgkmcnt(0)" ::: "memory");
    __threadfence();
    __syncthreads();
    if (tid == 0) atomicAdd(cnt, 1);
  };
  auto spin = [&](int* cnt, int target) {
    if (tid == 0) {
      while (__hip_atomic_load(cnt, __ATOMIC_ACQUIRE,
                               __HIP_MEMORY_SCOPE_AGENT) < target)
        __builtin_amdgcn_s_sleep(8);
    }
    __syncthreads();
  };

  if (bid >= 256) {
    if (bid < 496) {               // ---- pure fill role ----
      ntfill(1536LL + (long long)(bid - 256) * 27, 108);
      signal(fillcnt);
      return;
    }
    // ---- scan role: small fill, then scan+scatter ----
    const int s = bid - 496;
    ntfill(8016LL + (long long)s * 11, 44);
    signal(fillcnt);

    spin(donecnt, 256);            // gemm outputs (idx/gval/esum) ready
    int* sidx = (int*)LDS;         // 32 KB
    for (int i = tid; i < T_TOK / 4; i += 1024)
      ((int4*)sidx)[i] = ((const int4*)idx)[i];
    __syncthreads();               // sidx staged (overlapped with fill tail)
    spin(fillcnt, 512);            // all zeros landed; safe to scatter

    const int wid  = tid >> 6;
    const int lane = tid & 63;
    if (wid < 4) {
      const int e = s * 4 + wid;
      int carry = 0;
#pragma unroll 4
      for (int base = 0; base < T_TOK; base += 64) {
        const int t = base + lane;
        const bool flag = (sidx[t] == e);
        const unsigned long long mask = __ballot(flag);
        if (flag) {
          const int p = carry + __popcll(mask & ((1ull << lane) - 1ull));
          if (p < CAP) {
            const size_t off = ((size_t)t * NEXP + e) * CAP + p;
            out[1 + off]       = gval[t];
            out[1 + TEC + off] = 1.0f;
          }
        }
        carry += __popcll(mask);
      }
      if (lane == 0)               // ce uses pre-drop count = carry
        atomicAdd(out, esum[e] * (float)carry *
                       ((float)NEXP / ((float)T_TOK * (float)T_TOK)));
    }
    return;
  }

  // ---- GEMM role (R15 verbatim) ----
  const int t0 = bid * 32;

  const int wid  = tid >> 6;
  const int lane = tid & 63;
  const int tt   = wid & 1;
  const int et   = (wid >> 1) & 3;
  const int kc   = wid >> 3;
  const int mrow = lane & 15;
  const int kg   = lane >> 4;

  const int spl  = tid >> 9;
  const int su   = tid & 511;
  const int sexp = su >> 3;
  const int sq   = su & 7;
  const int sm   = sq ^ (sexp & 7);
  const short* bsrc0 = (spl ? wl : wh) + (size_t)sexp * MDIM +
                       (sm >> 2) * 2048 + (sm & 3) * 8;
  const int atok = tid >> 4;
  const int as   = tid & 15;
  const int apr  = (as >> 1) ^ (atok & 7);
  const float* asrc0 = x + (size_t)(t0 + atok) * MDIM +
                       (apr >> 2) * 2048 + (apr & 3) * 8 + (as & 1) * 4;

  const int w8 = __builtin_amdgcn_readfirstlane((tid >> 9) == 0 ? 1 : 0);

  const int tok   = tt * 16 + mrow;
  const int abyte = tok * 256 + (((kc * 4 + kg) ^ (tok & 7)) << 5);
  const int expi  = et * 16 + mrow;
  const int bbyte = expi * 128 + (((kc * 4 + kg) ^ (expi & 7)) << 4);

  f32x4 acc = {0.f, 0.f, 0.f, 0.f};

  auto stage = [&](int j, int buf) {
    const int b = buf * 8192;
    gll16(bsrc0 + j * 32, LDS + 24576 + spl * 24576 + b + su * 16);
    if (w8) gll16(asrc0 + j * 32, LDS + b + (tid << 4));
  };
  auto compute = [&](int kb, int buf) {
    const int b = buf * 8192;
    const char* ab = LDS + b;
    const f32x4 a0 = *(const f32x4*)(ab + abyte);
    const f32x4 a1 = *(const f32x4*)(ab + abyte + 16);
    const float fa[8] = {a0[0], a0[1], a0[2], a0[3], a1[0], a1[1], a1[2], a1[3]};
    bf16x8 ah, al;
    split8(fa, ah, al);
    const bf16x8 bhv = *(const bf16x8*)(LDS + 24576 + b + bbyte);
    const bf16x8 blv = *(const bf16x8*)(LDS + 49152 + b + bbyte);
    acc = __builtin_amdgcn_mfma_f32_16x16x32_bf16(ah, bhv, acc, 0, 0, 0);
    acc = __builtin_amdgcn_mfma_f32_16x16x32_bf16(ah, blv, acc, 0, 0, 0);
    acc = __builtin_amdgcn_mfma_f32_16x16x32_bf16(al, bhv, acc, 0, 0, 0);
  };

  stage(0, 0); stage(1, 1);

  int cb = 0, sb = 2;
#pragma unroll 3
  for (int kb = 0; kb < 62; ++kb) {
    if (w8) vwait<2>(); else vwait<1>();
    barrier_now();
    stage(kb + 2, sb);
    compute(kb, cb);
    cb = (cb == 2) ? 0 : cb + 1;
    sb = (sb == 2) ? 0 : sb + 1;
  }
  if (w8) vwait<2>(); else vwait<1>();
  barrier_now(); compute(62, 2);
  vwait<0>();
  barrier_now(); compute(63, 0);

  __syncthreads();

  // epilogue: K-pair reduce + softmax/argmax (C/D: col=lane&15, row=kg*4+r)
  float* redF = (float*)LDS;
#pragma unroll
  for (int r = 0; r < 4; ++r)
    redF[(kc * 32 + tt * 16 + kg * 4 + r) * 64 + et * 16 + mrow] = acc[r];
  __syncthreads();

  float gl = 0.f;
#pragma unroll
  for (int j = 0; j < 2; ++j) {
    const int tk = wid * 2 + j;
    const float v = redF[tk * 64 + lane] + redF[(32 + tk) * 64 + lane];
    float m = v; int mi = lane;
#pragma unroll
    for (int d = 32; d >= 1; d >>= 1) {
      const float om = __shfl_xor(m, d);
      const int   oi = __shfl_xor(mi, d);
      if (om > m || (om == m && oi < mi)) { m = om; mi = oi; }
    }
    const float e = expf(v - m);
    float denom = e;
#pragma unroll
    for (int d = 32; d >= 1; d >>= 1) denom += __shfl_xor(denom, d);
    gl += e / denom;
    if (lane == 0) { idx[t0 + tk] = mi; gval[t0 + tk] = 1.0f / denom; }
  }

  float* sgF = (float*)(LDS + 16384);
  sgF[wid * 64 + lane] = gl;
  __syncthreads();
  if (tid < 64) {
    float s = 0.f;
#pragma unroll
    for (int w = 0; w < 16; ++w) s += sgF[w * 64 + tid];
    atomicAdd(&esum[tid], s);
  }

  signal(donecnt);                 // idx/gval/esum globally visible

  // NT-fill tail: adds write capacity in the post-gemm phase
  ntfill((long long)bid * 6, 24);
  if (bid == 0 && tid == 0) out[OUTN - 1] = 0.f;
  signal(fillcnt);
}

extern "C" void kernel_launch(void* const* d_in, const int* in_sizes, int n_in,
                              void* d_out, int out_size, void* d_ws, size_t ws_size,
                              hipStream_t stream) {
  const float* x  = (const float*)d_in[0];
  const float* wg = (const float*)d_in[1];
  float* out = (float*)d_out;

  short* wh   = (short*)d_ws;                               // 64*4096 bf16
  short* wl   = wh + (size_t)NEXP * MDIM;
  int*   idx  = (int*)(wl + (size_t)NEXP * MDIM);
  float* gval = (float*)(idx + T_TOK);
  float* esum = (float*)(gval + T_TOK);
  int*   cnts = (int*)(esum + NEXP);

  wsplit<<<(NEXP * MDIM / 4) / 256, 256, 0, stream>>>(wg, wh, wl, esum, cnts);
  fused<<<512, 1024, 0, stream>>>(x, wh, wl, idx, gval, esum, cnts, out);
}

// Round 17
// 139.624 us; speedup vs baseline: 3.5833x; 3.5833x over previous
//
#include <hip/hip_runtime.h>
#include <hip/hip_bf16.h>
#include <cstdint>
#include <cstddef>

#define T_TOK 8192
#define MDIM  4096
#define NEXP  64
#define CAP   128
#define TEC   ((size_t)T_TOK * NEXP * CAP)        // 67,108,864
#define OUTN  ((size_t)(1 + 2 * TEC))             // 134,217,729 floats

typedef __attribute__((ext_vector_type(8))) short bf16x8;   // 8 bf16 = 4 VGPR
typedef __attribute__((ext_vector_type(4))) float f32x4;    // MFMA acc

// split f32 -> hi bf16 + lo bf16 (residual), |err| ~ 2^-18 relative
__device__ __forceinline__ void split8(const float* f, bf16x8& h, bf16x8& l) {
#pragma unroll
  for (int j = 0; j < 8; ++j) {
    const __hip_bfloat16 hb = __float2bfloat16(f[j]);
    const float r = f[j] - __bfloat162float(hb);
    h[j] = __builtin_bit_cast(short, hb);
    l[j] = __builtin_bit_cast(short, __float2bfloat16(r));
  }
}

// async global->LDS, 16 bytes per lane (linear LDS dest: wavebase + lane*16)
__device__ __forceinline__ void gll16(const void* g, void* l) {
  __builtin_amdgcn_global_load_lds(
      (const __attribute__((address_space(1))) void*)g,
      (__attribute__((address_space(3))) void*)l, 16, 0, 0);
}

template <int N>
__device__ __forceinline__ void vwait() {
  if constexpr (N == 0)      asm volatile("s_waitcnt vmcnt(0) lgkmcnt(0)" ::: "memory");
  else if constexpr (N == 1) asm volatile("s_waitcnt vmcnt(1) lgkmcnt(0)" ::: "memory");
  else                       asm volatile("s_waitcnt vmcnt(2) lgkmcnt(0)" ::: "memory");
}
__device__ __forceinline__ void barrier_now() {
  __builtin_amdgcn_s_barrier();
  asm volatile("" ::: "memory");
}

// ---------------------------------------------------------------------------
// One-time: wg (f32, [E][D]) -> wh/wl bf16 planes; zero esum.
// ---------------------------------------------------------------------------
__global__ __launch_bounds__(256) void wsplit(
    const float* __restrict__ wg, short* __restrict__ wh,
    short* __restrict__ wl, float* __restrict__ esum) {
  const int i = blockIdx.x * 256 + threadIdx.x;       // float4 granule
  const float4 v = ((const float4*)wg)[i];
  const float a[4] = {v.x, v.y, v.z, v.w};
  short4 h, l;
  short* hp = &h.x; short* lp = &l.x;
#pragma unroll
  for (int j = 0; j < 4; ++j) {
    const __hip_bfloat16 hb = __float2bfloat16(a[j]);
    const float r = a[j] - __bfloat162float(hb);
    hp[j] = __builtin_bit_cast(short, hb);
    lp[j] = __builtin_bit_cast(short, __float2bfloat16(r));
  }
  ((short4*)wh)[i] = h;
  ((short4*)wl)[i] = l;
  if (blockIdx.x == 0 && threadIdx.x < NEXP) esum[threadIdx.x] = 0.f;
}

// ---------------------------------------------------------------------------
// Fused GEMM + zero-fill via co-resident roles (R15 structure). NO cross-
// block sync (R16 lesson: device-scope fences/acquire polling poison L2).
// Grid = [256 gemm][256 fill], 1024 thr, 2 blk/CU (72KB LDS each).
//   fill role: 26 units of NT zeros (unit = 4096 float4 = 64KB).
//   gemm role: R15 GEMM+softmax epilogue, then a 6-unit NT fill tail --
//              uses gemm CUs' idle store capacity in the post-gemm phase.
// 256*6 + 256*26 = 8192 units = exact cover of out[0..OUTN-2].
// Downstream scan_scatter is a separate launch -> kernel-boundary ordering.
// ---------------------------------------------------------------------------
__global__ __launch_bounds__(1024, 8) void gemm_fill_softmax(
    const float* __restrict__ x, const short* __restrict__ wh,
    const short* __restrict__ wl, int* __restrict__ idx,
    float* __restrict__ gval, float* __restrict__ esum,
    float* __restrict__ out) {
  __shared__ __align__(16) char LDS[73728];           // 72 KB
  const int tid = threadIdx.x;
  const int bid = blockIdx.x;

  const f32x4 zv = {0.f, 0.f, 0.f, 0.f};
  f32x4* o4 = (f32x4*)out;
  auto ntfill = [&](long long startUnit, int iters) {
    size_t g = (size_t)startUnit * 4096 + tid;
#pragma unroll 4
    for (int i = 0; i < iters; ++i) {
      __builtin_nontemporal_store(zv, o4 + g);
      g += 1024;
    }
  };

  if (bid >= 256) {              // ---- fill role: NT zero-stream ----
    ntfill(1536LL + (long long)(bid - 256) * 26, 104);
    return;
  }

  // ---- GEMM role (R15 verbatim) ----
  const int t0 = bid * 32;

  const int wid  = tid >> 6;
  const int lane = tid & 63;
  const int tt   = wid & 1;
  const int et   = (wid >> 1) & 3;
  const int kc   = wid >> 3;
  const int mrow = lane & 15;
  const int kg   = lane >> 4;

  const int spl  = tid >> 9;
  const int su   = tid & 511;
  const int sexp = su >> 3;
  const int sq   = su & 7;
  const int sm   = sq ^ (sexp & 7);
  const short* bsrc0 = (spl ? wl : wh) + (size_t)sexp * MDIM +
                       (sm >> 2) * 2048 + (sm & 3) * 8;
  const int atok = tid >> 4;
  const int as   = tid & 15;
  const int apr  = (as >> 1) ^ (atok & 7);
  const float* asrc0 = x + (size_t)(t0 + atok) * MDIM +
                       (apr >> 2) * 2048 + (apr & 3) * 8 + (as & 1) * 4;

  const int w8 = __builtin_amdgcn_readfirstlane((tid >> 9) == 0 ? 1 : 0);

  const int tok   = tt * 16 + mrow;
  const int abyte = tok * 256 + (((kc * 4 + kg) ^ (tok & 7)) << 5);
  const int expi  = et * 16 + mrow;
  const int bbyte = expi * 128 + (((kc * 4 + kg) ^ (expi & 7)) << 4);

  f32x4 acc = {0.f, 0.f, 0.f, 0.f};

  auto stage = [&](int j, int buf) {
    const int b = buf * 8192;
    gll16(bsrc0 + j * 32, LDS + 24576 + spl * 24576 + b + su * 16);
    if (w8) gll16(asrc0 + j * 32, LDS + b + (tid << 4));
  };
  auto compute = [&](int kb, int buf) {
    const int b = buf * 8192;
    const char* ab = LDS + b;
    const f32x4 a0 = *(const f32x4*)(ab + abyte);
    const f32x4 a1 = *(const f32x4*)(ab + abyte + 16);
    const float fa[8] = {a0[0], a0[1], a0[2], a0[3], a1[0], a1[1], a1[2], a1[3]};
    bf16x8 ah, al;
    split8(fa, ah, al);
    const bf16x8 bhv = *(const bf16x8*)(LDS + 24576 + b + bbyte);
    const bf16x8 blv = *(const bf16x8*)(LDS + 49152 + b + bbyte);
    acc = __builtin_amdgcn_mfma_f32_16x16x32_bf16(ah, bhv, acc, 0, 0, 0);
    acc = __builtin_amdgcn_mfma_f32_16x16x32_bf16(ah, blv, acc, 0, 0, 0);
    acc = __builtin_amdgcn_mfma_f32_16x16x32_bf16(al, bhv, acc, 0, 0, 0);
  };

  stage(0, 0); stage(1, 1);

  int cb = 0, sb = 2;
#pragma unroll 3
  for (int kb = 0; kb < 62; ++kb) {
    if (w8) vwait<2>(); else vwait<1>();
    barrier_now();
    stage(kb + 2, sb);
    compute(kb, cb);
    cb = (cb == 2) ? 0 : cb + 1;
    sb = (sb == 2) ? 0 : sb + 1;
  }
  if (w8) vwait<2>(); else vwait<1>();
  barrier_now(); compute(62, 2);
  vwait<0>();
  barrier_now(); compute(63, 0);

  __syncthreads();                         // staging drained; reuse LDS

  // ---- epilogue: K-pair reduce + softmax/argmax ----
  // C/D layout: col = lane&15 (expert), row = kg*4 + r (token)
  float* redF = (float*)LDS;               // [kc(2)][tok(32)][exp(64)] = 16KB
#pragma unroll
  for (int r = 0; r < 4; ++r)
    redF[(kc * 32 + tt * 16 + kg * 4 + r) * 64 + et * 16 + mrow] = acc[r];
  __syncthreads();

  float gl = 0.f;
#pragma unroll
  for (int j = 0; j < 2; ++j) {
    const int tk = wid * 2 + j;
    const float v = redF[tk * 64 + lane] + redF[(32 + tk) * 64 + lane];
    float m = v; int mi = lane;
#pragma unroll
    for (int d = 32; d >= 1; d >>= 1) {
      const float om = __shfl_xor(m, d);
      const int   oi = __shfl_xor(mi, d);
      if (om > m || (om == m && oi < mi)) { m = om; mi = oi; }
    }
    const float e = expf(v - m);
    float denom = e;
#pragma unroll
    for (int d = 32; d >= 1; d >>= 1) denom += __shfl_xor(denom, d);
    gl += e / denom;
    if (lane == 0) { idx[t0 + tk] = mi; gval[t0 + tk] = 1.0f / denom; }
  }

  float* sgF = (float*)(LDS + 16384);      // [16][64], disjoint from red
  sgF[wid * 64 + lane] = gl;
  __syncthreads();
  if (tid < 64) {
    float s = 0.f;
#pragma unroll
    for (int w = 0; w < 16; ++w) s += sgF[w * 64 + tid];
    atomicAdd(&esum[tid], s);
  }

  // ---- NT fill tail: idle store capacity after gemm (no sync needed) ----
  ntfill((long long)bid * 6, 24);
  if (bid == 0 && tid == 0) out[OUTN - 1] = 0.f;
}

// ---------------------------------------------------------------------------
// Per-expert scan + scatter + l_aux. One wave per expert, idx staged in LDS.
// Separate launch after the fused kernel -> all zeros/gemm results visible.
// ---------------------------------------------------------------------------
__global__ __launch_bounds__(256) void scan_scatter(
    const int* __restrict__ idx, const float* __restrict__ gval,
    const float* __restrict__ esum, float* __restrict__ out) {
  __shared__ int sidx[T_TOK];           // 32 KB
  const int tid = threadIdx.x;
  for (int i = tid; i < T_TOK / 4; i += 256)
    ((int4*)sidx)[i] = ((const int4*)idx)[i];
  __syncthreads();

  const int e    = blockIdx.x * 4 + (tid >> 6);
  const int lane = tid & 63;
  int carry = 0;
#pragma unroll 4
  for (int base = 0; base < T_TOK; base += 64) {
    const int t = base + lane;
    const bool flag = (sidx[t] == e);
    const unsigned long long mask = __ballot(flag);
    if (flag) {
      const int p = carry + __popcll(mask & ((1ull << lane) - 1ull));
      if (p < CAP) {
        const size_t off = ((size_t)t * NEXP + e) * CAP + p;
        out[1 + off]       = gval[t];
        out[1 + TEC + off] = 1.0f;
      }
    }
    carry += __popcll(mask);
  }
  if (lane == 0)                        // ce uses pre-drop count = carry
    atomicAdd(out, esum[e] * (float)carry *
                   ((float)NEXP / ((float)T_TOK * (float)T_TOK)));
}

extern "C" void kernel_launch(void* const* d_in, const int* in_sizes, int n_in,
                              void* d_out, int out_size, void* d_ws, size_t ws_size,
                              hipStream_t stream) {
  const float* x  = (const float*)d_in[0];
  const float* wg = (const float*)d_in[1];
  float* out = (float*)d_out;

  short* wh   = (short*)d_ws;                               // 64*4096 bf16
  short* wl   = wh + (size_t)NEXP * MDIM;
  int*   idx  = (int*)(wl + (size_t)NEXP * MDIM);
  float* gval = (float*)(idx + T_TOK);
  float* esum = (float*)(gval + T_TOK);

  wsplit<<<(NEXP * MDIM / 4) / 256, 256, 0, stream>>>(wg, wh, wl, esum);
  gemm_fill_softmax<<<512, 1024, 0, stream>>>(x, wh, wl, idx, gval, esum, out);
  scan_scatter<<<NEXP / 4, 256, 0, stream>>>(idx, gval, esum, out);
}